// Round 1
// baseline (1502.023 us; speedup 1.0000x reference)
//
#include <hip/hip_runtime.h>
#include <math.h>

#define E 1152
#define H 16
#define HD 72
#define B 32
#define S 4096
#define IDIM 4304

#define NEGF (-3.402823466e38f)
#define SCALE 0.1178511301977579f  // 1/sqrt(72)

__device__ __forceinline__ float wredsum(float v){
  v += __shfl_xor(v,32); v += __shfl_xor(v,16); v += __shfl_xor(v,8);
  v += __shfl_xor(v,4);  v += __shfl_xor(v,2);  v += __shfl_xor(v,1);
  return v;
}
__device__ __forceinline__ float wredmax(float v){
  v = fmaxf(v,__shfl_xor(v,32)); v = fmaxf(v,__shfl_xor(v,16)); v = fmaxf(v,__shfl_xor(v,8));
  v = fmaxf(v,__shfl_xor(v,4));  v = fmaxf(v,__shfl_xor(v,2));  v = fmaxf(v,__shfl_xor(v,1));
  return v;
}

// q[j] = probe . wq[j,:] + bq[j]   (j < E), one wave per j
__global__ void k_q(const float* __restrict__ probe, const float* __restrict__ ipw,
                    const float* __restrict__ ipb, float* __restrict__ q){
  int tid = threadIdx.x, lane = tid & 63, w = tid >> 6;
  int j = blockIdx.x*4 + w;
  const float* wr = ipw + (size_t)j*E;
  float s = 0.f;
  #pragma unroll
  for (int t=0;t<18;++t){ int e = lane + 64*t; s = fmaf(probe[e], wr[e], s); }
  s = wredsum(s);
  if (lane==0) q[j] = s + ipb[j];
}

// qk[h*E+e] = sum_d q[h*72+d]*wk[h*72+d, e]; cbias[h] = q[h]·bk_h
__global__ void k_qk(const float* __restrict__ q, const float* __restrict__ ipw,
                     const float* __restrict__ ipb, float* __restrict__ qk,
                     float* __restrict__ cb){
  int idx = blockIdx.x*256 + threadIdx.x;   // < H*E
  int h = idx / E, e = idx % E;
  float s = 0.f;
  #pragma unroll 8
  for (int d=0; d<HD; ++d)
    s = fmaf(q[h*HD+d], ipw[(size_t)(E + h*HD + d)*E + e], s);
  qk[idx] = s;
  if (idx < H){
    float c = 0.f;
    for (int d=0; d<HD; ++d) c = fmaf(q[idx*HD+d], ipb[E + idx*HD + d], c);
    cb[idx] = c;
  }
}

// scores[b,h,s] = SCALE*(hidden[b,s,:]·qk[h,:] + cb[h]) + (1-mask)*NEG
// block = 256 thr (4 waves), 4 rows/wave, qk staged in LDS in two 8-head phases
__global__ __launch_bounds__(256) void k_scores(
    const float* __restrict__ hidden, const float* __restrict__ qk,
    const float* __restrict__ cb, const int* __restrict__ mask,
    float* __restrict__ scores){
  __shared__ float qk_lds[8*E];          // 36864 B
  int tid = threadIdx.x, lane = tid & 63, w = tid >> 6;
  int r_base = blockIdx.x*16 + w*4;
  // preload 4 hidden rows into registers (72 VGPR)
  float hv[4][18];
  #pragma unroll
  for (int rr=0; rr<4; ++rr){
    const float* hp = hidden + (size_t)(r_base+rr)*E + lane;
    #pragma unroll
    for (int t=0;t<18;++t) hv[rr][t] = hp[t*64];
  }
  #pragma unroll
  for (int ph=0; ph<2; ++ph){
    __syncthreads();
    for (int i=tid; i<8*E; i+=256) qk_lds[i] = qk[ph*8*E + i];
    __syncthreads();
    float acc[4][8];
    #pragma unroll
    for (int rr=0;rr<4;++rr)
      #pragma unroll
      for (int h=0;h<8;++h) acc[rr][h]=0.f;
    #pragma unroll
    for (int t=0;t<18;++t){
      int e = lane + 64*t;
      #pragma unroll
      for (int h=0;h<8;++h){
        float qv = qk_lds[h*E + e];
        #pragma unroll
        for (int rr=0;rr<4;++rr) acc[rr][h] = fmaf(hv[rr][t], qv, acc[rr][h]);
      }
    }
    #pragma unroll
    for (int rr=0;rr<4;++rr){
      #pragma unroll
      for (int h=0;h<8;++h){
        float s_ = wredsum(acc[rr][h]);
        if (lane == rr*8+h){
          int row = r_base + rr;
          int b = row >> 12, s = row & (S-1);
          int hh = ph*8 + h;
          float addm = (1.0f - (float)mask[(size_t)b*S + s]) * NEGF;
          scores[((size_t)(b*H + hh))*S + s] = SCALE*(s_ + cb[hh]) + addm;
        }
      }
    }
  }
}

// in-place softmax over last dim, one block per (b,h)
__global__ void k_softmax(float* __restrict__ sc){
  __shared__ float red[8];
  int tid = threadIdx.x, lane = tid & 63, w = tid >> 6;
  float* p = sc + (size_t)blockIdx.x*S;
  float m = -INFINITY;
  for (int i=tid;i<S;i+=256) m = fmaxf(m, p[i]);
  m = wredmax(m);
  if (lane==0) red[w]=m;
  __syncthreads();
  m = fmaxf(fmaxf(red[0],red[1]), fmaxf(red[2],red[3]));
  float sum = 0.f;
  for (int i=tid;i<S;i+=256){ float e_ = __expf(p[i]-m); p[i]=e_; sum+=e_; }
  sum = wredsum(sum);
  if (lane==0) red[4+w]=sum;
  __syncthreads();
  float inv = 1.0f/(red[4]+red[5]+red[6]+red[7]);
  for (int i=tid;i<S;i+=256) p[i] *= inv;
}

// partial ctx over an s-slice: part[b,sl,h,e] = sum_{s in slice} attn[b,h,s]*hidden[b,s,e]
__global__ __launch_bounds__(256) void k_ctxpart(
    const float* __restrict__ hidden, const float* __restrict__ attn,
    float* __restrict__ part, int s_per){
  int b = blockIdx.x, sl = blockIdx.y, tid = threadIdx.x;
  float acc[80];
  #pragma unroll
  for (int i=0;i<80;++i) acc[i]=0.f;
  int s0 = sl*s_per;
  #pragma unroll 2
  for (int s=s0; s<s0+s_per; ++s){
    const float* hp = hidden + ((size_t)b*S + s)*E;
    float hv[5];
    #pragma unroll
    for (int k=0;k<4;++k) hv[k] = hp[tid + 256*k];
    hv[4] = (tid < 128) ? hp[tid + 1024] : 0.f;
    #pragma unroll
    for (int h=0;h<H;++h){
      float a = attn[((size_t)(b*H + h))*S + s];   // block-uniform -> scalar
      #pragma unroll
      for (int k=0;k<5;++k) acc[h*5+k] = fmaf(a, hv[k], acc[h*5+k]);
    }
  }
  size_t base = ((size_t)(b*gridDim.y + sl))*H*E;
  #pragma unroll
  for (int h=0;h<H;++h)
    #pragma unroll
    for (int k=0;k<5;++k){
      int e = tid + 256*k;
      if (e < E) part[base + (size_t)h*E + e] = acc[h*5+k];
    }
}

__global__ void k_ctxred(const float* __restrict__ part, float* __restrict__ ctx, int slices){
  int idx = blockIdx.x*256 + threadIdx.x;  // < B*H*E
  int b = idx / (H*E); int he = idx % (H*E);
  float s = 0.f;
  for (int sl=0; sl<slices; ++sl) s += part[((size_t)(b*slices+sl))*(H*E) + he];
  ctx[idx] = s;
}

// pooled[b, j] = wv[j,:]·ctx[b, j/72, :] + bv[j]   (one wave per j, acc over 32 b)
__global__ void k_pool(const float* __restrict__ ctx, const float* __restrict__ ipw,
                       const float* __restrict__ ipb, float* __restrict__ pooled){
  int tid = threadIdx.x, lane = tid & 63, w = tid >> 6;
  int j = blockIdx.x*4 + w;
  int h = j / HD;
  const float* wr = ipw + (size_t)2*E*E + (size_t)j*E;
  float acc[32];
  #pragma unroll
  for (int b_=0;b_<32;++b_) acc[b_]=0.f;
  #pragma unroll
  for (int t=0;t<18;++t){
    int e = lane + 64*t;
    float wv = wr[e];
    #pragma unroll
    for (int b_=0;b_<32;++b_)
      acc[b_] = fmaf(wv, ctx[(size_t)(b_*H + h)*E + e], acc[b_]);
  }
  #pragma unroll
  for (int b_=0;b_<32;++b_){
    float s = wredsum(acc[b_]);
    if (lane==b_) pooled[(size_t)b_*E + j] = s + ipb[2*E + j];
  }
}

// resid[b,i] = out_w[i,:]·pooled[b,:] + out_b[i]
__global__ void k_outproj(const float* __restrict__ pooled, const float* __restrict__ ow,
                          const float* __restrict__ ob, float* __restrict__ resid){
  int tid = threadIdx.x, lane = tid & 63, w = tid >> 6;
  int i = blockIdx.x*4 + w;
  const float* wr = ow + (size_t)i*E;
  float acc[32];
  #pragma unroll
  for (int b_=0;b_<32;++b_) acc[b_]=0.f;
  #pragma unroll
  for (int t=0;t<18;++t){
    int e = lane + 64*t;
    float wv = wr[e];
    #pragma unroll
    for (int b_=0;b_<32;++b_)
      acc[b_] = fmaf(wv, pooled[(size_t)b_*E + e], acc[b_]);
  }
  #pragma unroll
  for (int b_=0;b_<32;++b_){
    float s = wredsum(acc[b_]);
    if (lane==b_) resid[(size_t)b_*E + i] = s + ob[i];
  }
}

__global__ void k_ln(const float* __restrict__ resid, const float* __restrict__ g,
                     const float* __restrict__ be, float* __restrict__ x){
  __shared__ float red[8];
  int b = blockIdx.x, tid = threadIdx.x, lane = tid & 63, w = tid >> 6;
  const float* r = resid + (size_t)b*E;
  float s = 0.f, s2 = 0.f;
  for (int e=tid; e<E; e+=256){ float v = r[e]; s += v; s2 = fmaf(v,v,s2); }
  s = wredsum(s); s2 = wredsum(s2);
  if (lane==0){ red[w]=s; red[4+w]=s2; }
  __syncthreads();
  float S1 = red[0]+red[1]+red[2]+red[3];
  float S2 = red[4]+red[5]+red[6]+red[7];
  float mu  = S1*(1.0f/E);
  float var = S2*(1.0f/E) - mu*mu;
  float inv = rsqrtf(var + 1e-6f);
  for (int e=tid; e<E; e+=256){
    float v = (r[e]-mu)*inv;
    x[(size_t)b*E + e] = v*g[e] + be[e];
  }
}

__device__ __forceinline__ float gelu_tanh(float u){
  float u3 = u*u*u;
  float t = tanhf(0.7978845608028654f*(u + 0.044715f*u3));
  return 0.5f*u*(1.0f+t);
}

// h1[b,i] = gelu(x[b,:]·fc1_w[i,:] + b1[i]); wave handles 2 i's, acc over 32 b
__global__ __launch_bounds__(256) void k_fc1(
    const float* __restrict__ x, const float* __restrict__ w1,
    const float* __restrict__ b1, float* __restrict__ h1){
  int tid = threadIdx.x, lane = tid & 63, w = tid >> 6;
  int wid = blockIdx.x*4 + w;      // < 2152
  int i0 = wid*2;
  float acc[2][32];
  #pragma unroll
  for (int ii=0;ii<2;++ii)
    #pragma unroll
    for (int b_=0;b_<32;++b_) acc[ii][b_]=0.f;
  #pragma unroll
  for (int t=0;t<18;++t){
    int e = lane + 64*t;
    float f0 = w1[(size_t)i0*E + e];
    float f1 = w1[(size_t)(i0+1)*E + e];
    #pragma unroll
    for (int b_=0;b_<32;++b_){
      float xv = x[(size_t)b_*E + e];
      acc[0][b_] = fmaf(f0, xv, acc[0][b_]);
      acc[1][b_] = fmaf(f1, xv, acc[1][b_]);
    }
  }
  #pragma unroll
  for (int ii=0;ii<2;++ii)
    #pragma unroll
    for (int b_=0;b_<32;++b_){
      float s = wredsum(acc[ii][b_]);
      if (lane==b_) h1[(size_t)b_*IDIM + i0 + ii] = gelu_tanh(s + b1[i0+ii]);
    }
}

// out[b,i] = resid[b,i] + h1[b,:]·fc2_w[i,:] + b2[i]
__global__ __launch_bounds__(256) void k_fc2(
    const float* __restrict__ h1, const float* __restrict__ w2,
    const float* __restrict__ b2, const float* __restrict__ resid,
    float* __restrict__ out){
  int tid = threadIdx.x, lane = tid & 63, w = tid >> 6;
  int wid = blockIdx.x*4 + w;      // < 576
  int i0 = wid*2;
  float acc[2][32];
  #pragma unroll
  for (int ii=0;ii<2;++ii)
    #pragma unroll
    for (int b_=0;b_<32;++b_) acc[ii][b_]=0.f;
  #pragma unroll 2
  for (int t=0;t<68;++t){
    int e = lane + 64*t;
    if (e < IDIM){
      float f0 = w2[(size_t)i0*IDIM + e];
      float f1 = w2[(size_t)(i0+1)*IDIM + e];
      #pragma unroll
      for (int b_=0;b_<32;++b_){
        float hvv = h1[(size_t)b_*IDIM + e];
        acc[0][b_] = fmaf(f0, hvv, acc[0][b_]);
        acc[1][b_] = fmaf(f1, hvv, acc[1][b_]);
      }
    }
  }
  #pragma unroll
  for (int ii=0;ii<2;++ii)
    #pragma unroll
    for (int b_=0;b_<32;++b_){
      float s = wredsum(acc[ii][b_]);
      if (lane==b_){
        int i = i0 + ii;
        out[(size_t)b_*E + i] = resid[(size_t)b_*E + i] + s + b2[i];
      }
    }
}

extern "C" void kernel_launch(void* const* d_in, const int* in_sizes, int n_in,
                              void* d_out, int out_size, void* d_ws, size_t ws_size,
                              hipStream_t stream){
  const float* hidden = (const float*)d_in[0];
  const int*   mask   = (const int*)d_in[1];
  const float* probe  = (const float*)d_in[2];
  const float* ipw    = (const float*)d_in[3];
  const float* ipb    = (const float*)d_in[4];
  const float* ow     = (const float*)d_in[5];
  const float* ob     = (const float*)d_in[6];
  const float* ln_g   = (const float*)d_in[7];
  const float* ln_b   = (const float*)d_in[8];
  const float* w1     = (const float*)d_in[9];
  const float* b1     = (const float*)d_in[10];
  const float* w2     = (const float*)d_in[11];
  const float* b2     = (const float*)d_in[12];
  float* out = (float*)d_out;
  float* ws  = (float*)d_ws;

  float* q  = ws;                 // E
  float* qk = ws + E;             // H*E
  float* cb = ws + E + H*E;       // H  (19584)
  float* sc = ws + 19600;         // B*H*S
  size_t off = 19600 + (size_t)B*H*S;

  int slices = 16;
  while (slices > 1){
    size_t need = off + (size_t)B*slices*H*E + (size_t)B*H*E
                + 3*(size_t)B*E + (size_t)B*IDIM;
    if (need*sizeof(float) <= ws_size) break;
    slices >>= 1;
  }
  float* part   = ws + off;  off += (size_t)B*slices*H*E;
  float* ctx    = ws + off;  off += (size_t)B*H*E;
  float* pooled = ws + off;  off += (size_t)B*E;
  float* resid  = ws + off;  off += (size_t)B*E;
  float* x      = ws + off;  off += (size_t)B*E;
  float* h1     = ws + off;

  k_q       <<<288, 256, 0, stream>>>(probe, ipw, ipb, q);
  k_qk      <<<72, 256, 0, stream>>>(q, ipw, ipb, qk, cb);
  k_scores  <<<8192, 256, 0, stream>>>(hidden, qk, cb, mask, sc);
  k_softmax <<<512, 256, 0, stream>>>(sc);
  k_ctxpart <<<dim3(B, slices), 256, 0, stream>>>(hidden, sc, part, S/slices);
  k_ctxred  <<<2304, 256, 0, stream>>>(part, ctx, slices);
  k_pool    <<<288, 256, 0, stream>>>(ctx, ipw, ipb, pooled);
  k_outproj <<<288, 256, 0, stream>>>(pooled, ow, ob, resid);
  k_ln      <<<32, 256, 0, stream>>>(resid, ln_g, ln_b, x);
  k_fc1     <<<538, 256, 0, stream>>>(x, w1, b1, h1);
  k_fc2     <<<144, 256, 0, stream>>>(h1, w2, b2, resid, out);
}